// Round 9
// baseline (354.958 us; speedup 1.0000x reference)
//
#include <hip/hip_runtime.h>
#include <hip/hip_bf16.h>

// B=8, N=2048, D=384, R=64, H=W=256.
// Inputs:  x (B,N,D) f32, segments (B,H,W) i32, prototypes (1,R,D) f32.
// Outputs (f32, concat): out (B,N,D) | segments (B,H,W) | loss (1) | C (B,N,R)
//
// Pipeline (8 dispatches):
//   memset(maskp+prox) ; k_proto ; k_seg ; k_csim (S normalized + colsum
//   partials + bf16 xT) ; k_lossfc (loss partials + C + Kbf) ; k_qk (P=mask.*
//   ChatChat^T bf16 -> ws) ; k_pv (out = diag(1/(P*1)) P X, 4-deep register
//   prefetch pipeline) ; k_segout (+ loss final reduce in block 0).
#define NB 8
#define NN 2048
#define ND 384
#define NR 64
#define OUT_ELEMS (NB*NN*ND)        // 6291456
#define SEG_ELEMS (NB*256*256)      // 524288
#define NBLK_LOSS (NB*NN/4)         // 4096

typedef float  f32x4  __attribute__((ext_vector_type(4)));
typedef short  bf16x8 __attribute__((ext_vector_type(8)));

__device__ inline float wsum(float v){
  #pragma unroll
  for(int o=32;o;o>>=1) v += __shfl_xor(v,o,64);
  return v;
}
__device__ inline float wmax(float v){
  #pragma unroll
  for(int o=32;o;o>>=1) v = fmaxf(v,__shfl_xor(v,o,64));
  return v;
}
__device__ inline unsigned short f2bf(float f){
  unsigned u = __float_as_uint(f);
  return (unsigned short)((u + 0x8000u) >> 16);
}

// ---- normalize prototypes -> kn (f32, unit rows) ----
__global__ void k_proto(const float* __restrict__ protos, float* __restrict__ kn){
  int r = blockIdx.x, l = threadIdx.x;
  float v[6]; float ss = 0.f;
  #pragma unroll
  for(int i=0;i<6;i++){ v[i] = protos[r*ND + l*6 + i]; ss += v[i]*v[i]; }
  ss = wsum(ss);
  float inv = 1.f / fmaxf(sqrtf(ss), 1e-8f);
  #pragma unroll
  for(int i=0;i<6;i++) kn[r*ND + l*6 + i] = v[i]*inv;
}

// ---- segments -> node mask + prox bitmask rows (64 u32/node) ----
__global__ void k_seg(const int* __restrict__ seg, float* __restrict__ mask, unsigned* prox){
  int idx = blockIdx.x*256 + threadIdx.x;
  int b = idx >> 16, p = idx & 65535, i = p >> 8, j = p & 255;
  int s = seg[idx];
  int base = b << 11;
  mask[base + s] = 1.f;
  if(j < 255){
    int s2 = seg[idx+1];
    if(s != s2 && s != 0 && s2 != 0){
      atomicOr(&prox[((size_t)(base+s))*64  + (s2>>5)], 1u<<(s2&31));
      atomicOr(&prox[((size_t)(base+s2))*64 + (s >>5)], 1u<<(s &31));
    }
  }
  if(i < 255){
    int s2 = seg[idx+256];
    if(s != s2 && s != 0 && s2 != 0){
      atomicOr(&prox[((size_t)(base+s))*64  + (s2>>5)], 1u<<(s2&31));
      atomicOr(&prox[((size_t)(base+s2))*64 + (s >>5)], 1u<<(s &31));
    }
  }
}

// ---- Csim GEMM: writes NORMALIZED s, colsum partials, bf16 xT ----
__global__ __launch_bounds__(256) void k_csim(const float* __restrict__ x,
                                              const float* __restrict__ kn,
                                              float* __restrict__ Sout,
                                              unsigned short* __restrict__ xTbf,
                                              float* __restrict__ part){
  __shared__ float xT[32*68];
  __shared__ float kT[32*68];
  __shared__ float xinvS[64];
  __shared__ float csh[16*64];
  int t = threadIdx.x;
  int m0 = blockIdx.x * 64;
  float acc[4][4] = {};
  int mload = t>>2, koff = (t&3)*8;
  int mb = (t>>4)*4, rb = (t&15)*4;
  float ssq = 0.f;
  for(int c=0;c<12;c++){
    int k0 = c*32;
    __syncthreads();
    const float4* xg = (const float4*)(x + (size_t)(m0+mload)*ND + k0 + koff);
    float4 a = xg[0], bq = xg[1];
    ssq += a.x*a.x + a.y*a.y + a.z*a.z + a.w*a.w
         + bq.x*bq.x + bq.y*bq.y + bq.z*bq.z + bq.w*bq.w;
    xT[(koff+0)*68+mload]=a.x;  xT[(koff+1)*68+mload]=a.y;  xT[(koff+2)*68+mload]=a.z;  xT[(koff+3)*68+mload]=a.w;
    xT[(koff+4)*68+mload]=bq.x; xT[(koff+5)*68+mload]=bq.y; xT[(koff+6)*68+mload]=bq.z; xT[(koff+7)*68+mload]=bq.w;
    const float4* kg = (const float4*)(kn + mload*ND + k0 + koff);
    float4 ka = kg[0], kb = kg[1];
    kT[(koff+0)*68+mload]=ka.x; kT[(koff+1)*68+mload]=ka.y; kT[(koff+2)*68+mload]=ka.z; kT[(koff+3)*68+mload]=ka.w;
    kT[(koff+4)*68+mload]=kb.x; kT[(koff+5)*68+mload]=kb.y; kT[(koff+6)*68+mload]=kb.z; kT[(koff+7)*68+mload]=kb.w;
    __syncthreads();
    {
      int k2 = t>>3, mo = (t&7)*8;
      const float* src = &xT[k2*68 + mo];
      float4 aa = *(const float4*)src;
      float4 bb = *(const float4*)(src+4);
      uint4 o;
      o.x = (unsigned)f2bf(aa.x) | ((unsigned)f2bf(aa.y)<<16);
      o.y = (unsigned)f2bf(aa.z) | ((unsigned)f2bf(aa.w)<<16);
      o.z = (unsigned)f2bf(bb.x) | ((unsigned)f2bf(bb.y)<<16);
      o.w = (unsigned)f2bf(bb.z) | ((unsigned)f2bf(bb.w)<<16);
      int bb2 = m0 >> 11, ml = m0 & 2047;
      *(uint4*)(xTbf + ((size_t)(bb2*ND + k0 + k2))*NN + ml + mo) = o;
    }
    for(int k=0;k<32;k++){
      float xv[4], kv[4];
      *(float4*)xv = *(const float4*)&xT[k*68+mb];
      *(float4*)kv = *(const float4*)&kT[k*68+rb];
      #pragma unroll
      for(int mi=0;mi<4;mi++)
        #pragma unroll
        for(int ri=0;ri<4;ri++) acc[mi][ri] += xv[mi]*kv[ri];
    }
  }
  ssq += __shfl_xor(ssq,1,64);
  ssq += __shfl_xor(ssq,2,64);
  if((t&3)==0) xinvS[mload] = 1.f / fmaxf(sqrtf(ssq), 1e-8f);
  __syncthreads();
  float sv[4][4];
  #pragma unroll
  for(int mi=0;mi<4;mi++){
    float xin = xinvS[mb+mi];
    float rsum = 0.f;
    #pragma unroll
    for(int ri=0;ri<4;ri++){
      float vv = (acc[mi][ri]*xin + 1.f)*0.5f;
      sv[mi][ri] = vv; rsum += vv;
    }
    rsum += __shfl_xor(rsum,1,64);
    rsum += __shfl_xor(rsum,2,64);
    rsum += __shfl_xor(rsum,4,64);
    rsum += __shfl_xor(rsum,8,64);
    float inv = 1.f/rsum;
    #pragma unroll
    for(int ri=0;ri<4;ri++) sv[mi][ri] *= inv;
    *(float4*)&Sout[(size_t)(m0+mb+mi)*NR + rb] = *(const float4*)sv[mi];
  }
  {
    float4 pc;
    pc.x = sv[0][0]+sv[1][0]+sv[2][0]+sv[3][0];
    pc.y = sv[0][1]+sv[1][1]+sv[2][1]+sv[3][1];
    pc.z = sv[0][2]+sv[1][2]+sv[2][2]+sv[3][2];
    pc.w = sv[0][3]+sv[1][3]+sv[2][3]+sv[3][3];
    *(float4*)&csh[(t>>4)*64 + rb] = pc;
  }
  __syncthreads();
  if(t < 64){
    float a = 0.f;
    #pragma unroll
    for(int g=0;g<16;g++) a += csh[g*64 + t];
    part[(size_t)blockIdx.x*64 + t] = a;
  }
}

// ---- DEC KL loss (partial stores) + C=softmax(s) in place + Kbf ----
__global__ void k_lossfc(float* Smat, const float* __restrict__ part,
                         const float* __restrict__ mask,
                         float* __restrict__ klp, float* __restrict__ mp,
                         unsigned short* __restrict__ Kbf){
  __shared__ float shk[4], shm[4];
  int w = threadIdx.x>>6, l = threadIdx.x&63;
  int node = blockIdx.x*4 + w;
  int b = node >> 11;
  float s = Smat[(size_t)node*NR + l];
  float csm = 0.f;
  #pragma unroll
  for(int c=0;c<32;c++) csm += part[(size_t)((b<<5)+c)*64 + l];
  float p = s*s/(csm + 1e-8f);
  float ps = wsum(p);
  float P = p/(ps + 1e-8f);
  float term = P*(logf(P + 1e-8f) - logf(s + 1e-8f));
  float kl = wsum(term);
  if(l==0){ float mv = mask[node]; shk[w] = kl*mv; shm[w] = mv; }
  float mx = wmax(s);
  float e = expf(s - mx);
  float Z = wsum(e);
  float c = e / Z;
  float cn2 = wsum(c*c);
  Smat[(size_t)node*NR + l] = c;
  Kbf[(size_t)node*NR + l] = f2bf(c * rsqrtf(cn2));
  __syncthreads();
  if(threadIdx.x==0){
    klp[blockIdx.x] = shk[0]+shk[1]+shk[2]+shk[3];
    mp [blockIdx.x] = shm[0]+shm[1]+shm[2]+shm[3];
  }
}

// ---- pass A: P tile (64x64) = mask .* (Chat Chat^T), bf16 -> ws ----
__global__ __launch_bounds__(256) void k_qk(const unsigned short* __restrict__ Kbf,
                                            const unsigned* __restrict__ prox,
                                            unsigned short* __restrict__ Pbf){
  __shared__ short Plds[64*72];
  int tid = threadIdx.x;
  int w = tid>>6, l = tid&63, q = l>>4, li = l&15;
  int b  = blockIdx.x & 7;
  int qt = (blockIdx.x>>3) & 31;
  int kt = blockIdx.x >> 8;
  const unsigned short* Kb = Kbf + (size_t)b*NN*NR;

  int arow = qt*64 + w*16 + li;
  bf16x8 af[2];
  af[0] = *(const bf16x8*)(Kb + (size_t)arow*NR + q*8);
  af[1] = *(const bf16x8*)(Kb + (size_t)arow*NR + 32 + q*8);
  f32x4 pacc[4] = {(f32x4)(0.f),(f32x4)(0.f),(f32x4)(0.f),(f32x4)(0.f)};
  #pragma unroll
  for(int f=0;f<4;f++){
    int brow = kt*64 + f*16 + li;
    bf16x8 b0 = *(const bf16x8*)(Kb + (size_t)brow*NR + q*8);
    bf16x8 b1 = *(const bf16x8*)(Kb + (size_t)brow*NR + 32 + q*8);
    pacc[f] = __builtin_amdgcn_mfma_f32_16x16x32_bf16(af[0], b0, pacc[f], 0,0,0);
    pacc[f] = __builtin_amdgcn_mfma_f32_16x16x32_bf16(af[1], b1, pacc[f], 0,0,0);
  }
  #pragma unroll
  for(int r=0;r<4;r++){
    int lrow = w*16 + q*4 + r;
    int grow = qt*64 + lrow;
    uint2 mw = *(const uint2*)(prox + ((size_t)(b*NN + grow))*64 + kt*2);
    if(qt==kt){
      if((lrow>>5)==0) mw.x |= 1u<<(lrow&31); else mw.y |= 1u<<(lrow&31);
    }
    #pragma unroll
    for(int f=0;f<4;f++){
      unsigned wd = (f<2) ? mw.x : mw.y;
      float v = ((wd >> ((f&1)*16 + li)) & 1u) ? pacc[f][r] : 0.f;
      Plds[lrow*72 + f*16 + li] = (short)f2bf(v);
    }
  }
  __syncthreads();
  {
    int row = tid>>2, sg = tid&3;
    const uint4* src = (const uint4*)&Plds[row*72 + sg*16];
    unsigned short* dst = Pbf + ((size_t)(b*NN + qt*64 + row))*NN + kt*64 + sg*16;
    uint4 v0 = src[0], v1 = *(const uint4*)((const short*)src + 8);
    *(uint4*)dst = v0;
    *(uint4*)(dst + 8) = v1;
  }
}

// ---- pass B: out = diag(1/(P*1)) P X. 4-deep register prefetch pipeline ----
// bid map: b=bid&7, ds=(bid>>3)&1, nt=bid>>4 -> the two blocks sharing a P
// row-tile are bid/bid+8 (same XCD, co-dispatched -> L2 hit on P).
// __launch_bounds__(256,2): grid-limited to 2 waves/SIMD, allow ~256 VGPR so
// the 28-load prefetch window (4 steps x 7 frags) stays in registers.
__global__ __launch_bounds__(256, 2) void k_pv(const unsigned short* __restrict__ Pbf,
                                               const unsigned short* __restrict__ xTbf,
                                               float* __restrict__ out){
  int tid = threadIdx.x;
  int w = tid>>6, l = tid&63, q = l>>4, li = l&15;
  int b  = blockIdx.x & 7;
  int ds = (blockIdx.x>>3) & 1;
  int nt = blockIdx.x >> 4;
  int base = nt*64;
  int dcb = ds*192 + w*48;
  const unsigned short* Pb  = Pbf  + (size_t)b*NN*NN;
  const unsigned short* xTb = xTbf + (size_t)b*ND*NN;

  f32x4 acc[4][3];
  #pragma unroll
  for(int nc=0;nc<4;nc++)
    #pragma unroll
    for(int t=0;t<3;t++) acc[nc][t] = (f32x4)(0.f);
  f32x4 rsacc[4] = {(f32x4)(0.f),(f32x4)(0.f),(f32x4)(0.f),(f32x4)(0.f)};
  bf16x8 ones;
  #pragma unroll
  for(int i=0;i<8;i++) ones[i] = (short)0x3F80;   // bf16 1.0

  const unsigned short* Ap = Pb + (size_t)(base + li)*NN + q*8;
  const unsigned short* Bp = xTb + (size_t)(dcb + li)*NN + q*8;

  bf16x8 afb[4][4], bfb[4][3];
  #pragma unroll
  for(int p=0;p<4;p++){
    int k0 = p*32;
    #pragma unroll
    for(int nc=0;nc<4;nc++) afb[p][nc] = *(const bf16x8*)(Ap + (size_t)nc*16*NN + k0);
    #pragma unroll
    for(int t=0;t<3;t++)    bfb[p][t]  = *(const bf16x8*)(Bp + (size_t)t*16*NN + k0);
  }

  #pragma unroll
  for(int s=0;s<64;s++){
    int pb = s & 3;
    if(s + 4 < 64){
      int k0 = (s+4)*32;
      int pn = (s+4) & 3;
      #pragma unroll
      for(int nc=0;nc<4;nc++) afb[pn][nc] = *(const bf16x8*)(Ap + (size_t)nc*16*NN + k0);
      #pragma unroll
      for(int t=0;t<3;t++)    bfb[pn][t]  = *(const bf16x8*)(Bp + (size_t)t*16*NN + k0);
    }
    #pragma unroll
    for(int nc=0;nc<4;nc++){
      #pragma unroll
      for(int t=0;t<3;t++)
        acc[nc][t] = __builtin_amdgcn_mfma_f32_16x16x32_bf16(afb[pb][nc], bfb[pb][t], acc[nc][t], 0,0,0);
      rsacc[nc] = __builtin_amdgcn_mfma_f32_16x16x32_bf16(afb[pb][nc], ones, rsacc[nc], 0,0,0);
    }
  }

  #pragma unroll
  for(int nc=0;nc<4;nc++)
    #pragma unroll
    for(int r=0;r<4;r++){
      int row = base + nc*16 + q*4 + r;
      float inv = 1.f/(rsacc[nc][r] + 1e-8f);
      float* orow = out + ((size_t)(b*NN + row))*ND + dcb;
      #pragma unroll
      for(int t=0;t<3;t++)
        orow[t*16 + li] = acc[nc][t][r] * inv;
    }
}

// ---- segout; block 0 also reduces the loss partials ----
__global__ void k_segout(const int* __restrict__ seg, float* __restrict__ o,
                         const float* __restrict__ klp, const float* __restrict__ mp,
                         float* __restrict__ outLoss){
  int tid = threadIdx.x;
  int i = blockIdx.x*256 + tid;
  o[i] = (float)seg[i];
  if(blockIdx.x==0){
    __shared__ float sa[4], sm[4];
    float a=0.f, m=0.f;
    for(int k=tid; k<NBLK_LOSS; k+=256){ a += klp[k]; m += mp[k]; }
    a = wsum(a); m = wsum(m);
    if((tid&63)==0){ sa[tid>>6]=a; sm[tid>>6]=m; }
    __syncthreads();
    if(tid==0)
      outLoss[0] = (sa[0]+sa[1]+sa[2]+sa[3])/((sm[0]+sm[1]+sm[2]+sm[3])+1e-8f);
  }
}

extern "C" void kernel_launch(void* const* d_in, const int* in_sizes, int n_in,
                              void* d_out, int out_size, void* d_ws, size_t ws_size,
                              hipStream_t stream) {
  const float* x      = (const float*)d_in[0];
  const int*   seg    = (const int*)d_in[1];
  const float* protos = (const float*)d_in[2];

  float* out     = (float*)d_out;                  // (B,N,D)
  float* outSeg  = out + OUT_ELEMS;                // (B,H,W)
  float* outLoss = outSeg + SEG_ELEMS;             // scalar
  float* outC    = outLoss + 1;                    // (B,N,R)

  // ws layout (~83 MB)
  unsigned short* xTbf = (unsigned short*)d_ws;            // 8*384*2048 bf16 (12.6MB)
  unsigned short* Kbf  = xTbf + (size_t)NB*ND*NN;          // 8*2048*64 bf16 (2MB)
  unsigned short* Pbf  = Kbf + (size_t)NB*NN*NR;           // 8*2048*2048 bf16 (64MB)
  float* kn      = (float*)(Pbf + (size_t)NB*NN*NN);       // 24576 f32
  float* maskp   = kn + NR*ND;                             // 16384  -- zero region start
  unsigned* prox = (unsigned*)(maskp + NB*NN);             // 8*2048*64 u32 (4MB) -- zero region end
  float* part    = (float*)(prox + (size_t)NB*NN*64);      // 8*32*64 (fully written)
  float* klp     = part + NB*32*64;                        // 4096 (fully written)
  float* mp      = klp + NBLK_LOSS;                        // 4096 (fully written)

  size_t zero_bytes = (size_t)NB*NN*4 + (size_t)NB*NN*64*4;   // maskp + prox
  hipMemsetAsync(maskp, 0, zero_bytes, stream);

  k_proto <<<dim3(NR),           dim3(64),  0, stream>>>(protos, kn);
  k_seg   <<<dim3(NB*65536/256), dim3(256), 0, stream>>>(seg, maskp, prox);
  k_csim  <<<dim3(NB*NN/64),     dim3(256), 0, stream>>>(x, kn, outC, xTbf, part);
  k_lossfc<<<dim3(NBLK_LOSS),    dim3(256), 0, stream>>>(outC, part, maskp, klp, mp, Kbf);
  k_qk    <<<dim3(8192),         dim3(256), 0, stream>>>(Kbf, prox, Pbf);
  k_pv    <<<dim3(512),          dim3(256), 0, stream>>>(Pbf, xTbf, out);
  k_segout<<<dim3(SEG_ELEMS/256),dim3(256), 0, stream>>>(seg, outSeg, klp, mp, outLoss);
}